// Round 2
// baseline (1984.097 us; speedup 1.0000x reference)
//
#include <hip/hip_runtime.h>
#include <hip/hip_bf16.h>
#include <stdint.h>

// ---------------- types / helpers ----------------
typedef __attribute__((ext_vector_type(4))) float f32x4;
typedef __attribute__((ext_vector_type(8))) short s16x8;          // MFMA bf16 frag
typedef __attribute__((ext_vector_type(8))) unsigned short u16x8;

#define LL 1024
#define DMODEL 2048
#define DI 4096
#define NSTATE 16
#define RDT 128
#define NEXP 8
#define IFF 5632

__device__ inline unsigned short f2bf(float f) {            // fp32 -> bf16 RNE
  unsigned int u = __builtin_bit_cast(unsigned int, f);
  u += 0x7fffu + ((u >> 16) & 1u);
  return (unsigned short)(u >> 16);
}
__device__ inline float bf2f(unsigned short h) {
  unsigned int u = ((unsigned int)h) << 16;
  return __builtin_bit_cast(float, u);
}
__device__ inline float wred64(float v) {
#pragma unroll
  for (int m = 32; m; m >>= 1) v += __shfl_xor(v, m, 64);
  return v;
}
__device__ inline f32x4 mfma16(s16x8 a, s16x8 b, f32x4 c) {
  return __builtin_amdgcn_mfma_f32_16x16x32_bf16(a, b, c, 0, 0, 0);
}

// ---------------- RMSNorm (optionally fused residual-add) ----------------
__global__ __launch_bounds__(256) void rmsnorm_k(
    const float* __restrict__ x, const float* __restrict__ w,
    const float* __restrict__ addin, float* __restrict__ resout,
    float* __restrict__ f32out, unsigned short* __restrict__ bf16out)
{
  int t = blockIdx.x, tid = threadIdx.x;
  size_t base = (size_t)t * DMODEL + tid * 8;
  f32x4 v0 = *(const f32x4*)(x + base);
  f32x4 v1 = *(const f32x4*)(x + base + 4);
  if (addin) {
    v0 += *(const f32x4*)(addin + base);
    v1 += *(const f32x4*)(addin + base + 4);
  }
  float ss = 0.f;
#pragma unroll
  for (int j = 0; j < 4; j++) ss += v0[j]*v0[j] + v1[j]*v1[j];
  ss = wred64(ss);
  __shared__ float sred[4];
  if ((tid & 63) == 0) sred[tid >> 6] = ss;
  __syncthreads();
  ss = sred[0] + sred[1] + sred[2] + sred[3];
  float sc = rsqrtf(ss * (1.f / DMODEL) + 1e-6f);
  if (resout) {
    *(f32x4*)(resout + base) = v0;
    *(f32x4*)(resout + base + 4) = v1;
  }
  f32x4 w0 = *(const f32x4*)(w + tid * 8);
  f32x4 w1 = *(const f32x4*)(w + tid * 8 + 4);
  f32x4 o0 = v0 * sc * w0, o1 = v1 * sc * w1;
  if (f32out) {
    *(f32x4*)(f32out + base) = o0;
    *(f32x4*)(f32out + base + 4) = o1;
  }
  if (bf16out) {
    u16x8 ob;
#pragma unroll
    for (int j = 0; j < 4; j++) { ob[j] = f2bf(o0[j]); ob[4 + j] = f2bf(o1[j]); }
    *(u16x8*)(bf16out + base) = ob;
  }
}

// ---------------- GEMM tiling constants ----------------
#define BM 128
#define BN 128
#define BK 32
#define LSTR 48   // 32 + 16 pad

// stage 16 bf16 elems/thread into LDS
__device__ inline void stage_a_bf16(const unsigned short* aptr, bool valid,
                                    unsigned short* l, int ar, int ac) {
  u16x8 a0 = {}, a1 = {};
  if (valid) {
    a0 = *(const u16x8*)(aptr);
    a1 = *(const u16x8*)(aptr + 8);
  }
  *(u16x8*)&l[ar * LSTR + ac] = a0;
  *(u16x8*)&l[ar * LSTR + ac + 8] = a1;
}
// stage 16 fp32 elems/thread, converted to bf16 (single precision level)
__device__ inline void stage_w_f32(const float* wptr, bool valid,
                                   unsigned short* l, int ar, int ac) {
  u16x8 b0 = {}, b1 = {};
  if (valid) {
    f32x4 f0 = *(const f32x4*)(wptr);
    f32x4 f1 = *(const f32x4*)(wptr + 4);
    f32x4 f2 = *(const f32x4*)(wptr + 8);
    f32x4 f3 = *(const f32x4*)(wptr + 12);
#pragma unroll
    for (int j = 0; j < 4; j++) {
      b0[j] = f2bf(f0[j]); b0[4 + j] = f2bf(f1[j]);
      b1[j] = f2bf(f2[j]); b1[4 + j] = f2bf(f3[j]);
    }
  }
  *(u16x8*)&l[ar * LSTR + ac] = b0;
  *(u16x8*)&l[ar * LSTR + ac + 8] = b1;
}
// stage 16 fp32 elems/thread, split into hi/lo bf16 (double-bf16 precision)
__device__ inline void stage_split(const float* ptr, bool valid,
                                   unsigned short* lh, unsigned short* ll,
                                   int ar, int ac) {
  u16x8 h0 = {}, h1 = {}, l0 = {}, l1 = {};
  if (valid) {
    f32x4 f0 = *(const f32x4*)(ptr);
    f32x4 f1 = *(const f32x4*)(ptr + 4);
    f32x4 f2 = *(const f32x4*)(ptr + 8);
    f32x4 f3 = *(const f32x4*)(ptr + 12);
#pragma unroll
    for (int j = 0; j < 4; j++) {
      unsigned short h;
      h = f2bf(f0[j]); h0[j]     = h; l0[j]     = f2bf(f0[j] - bf2f(h));
      h = f2bf(f1[j]); h0[4 + j] = h; l0[4 + j] = f2bf(f1[j] - bf2f(h));
      h = f2bf(f2[j]); h1[j]     = h; l1[j]     = f2bf(f2[j] - bf2f(h));
      h = f2bf(f3[j]); h1[4 + j] = h; l1[4 + j] = f2bf(f3[j] - bf2f(h));
    }
  }
  *(u16x8*)&lh[ar * LSTR + ac]     = h0;
  *(u16x8*)&lh[ar * LSTR + ac + 8] = h1;
  *(u16x8*)&ll[ar * LSTR + ac]     = l0;
  *(u16x8*)&ll[ar * LSTR + ac + 8] = l1;
}

// ---------------- split-bf16 GEMM: C[M,N] = A[M,K](f32) * W[N,K]^T(f32) ----------------
// 3-term: Ah*Bh + Ah*Bl + Al*Bh  -> ~2^-16 relative error (routing-critical path)
// EPI: 0 = plain, 1 = softplus(v + bias[col])
template<int EPI>
__global__ __launch_bounds__(256) void gemm_nt_split_k(
    const float* __restrict__ A, const float* __restrict__ W,
    float* __restrict__ C, int M, int N, int K, const float* __restrict__ bias)
{
  __shared__ unsigned short lAh[BM * LSTR];
  __shared__ unsigned short lAl[BM * LSTR];
  __shared__ unsigned short lBh[BN * LSTR];
  __shared__ unsigned short lBl[BN * LSTR];
  int tid = threadIdx.x;
  int n0 = blockIdx.x * BN, m0 = blockIdx.y * BM;
  int lane = tid & 63, wave = tid >> 6;
  int wm = (wave >> 1) * 64, wn = (wave & 1) * 64;
  int lrow = lane & 15, lk = (lane >> 4) * 8;
  int ar = tid >> 1, ac = (tid & 1) * 16;
  bool av = (m0 + ar) < M;
  bool wv = (n0 + ar) < N;
  const float* aptr = A + (size_t)(av ? (m0 + ar) : 0) * K + ac;
  const float* wptr = W + (size_t)(wv ? (n0 + ar) : 0) * K + ac;
  f32x4 acc[4][4] = {};
  for (int k0 = 0; k0 < K; k0 += BK) {
    stage_split(aptr + k0, av, lAh, lAl, ar, ac);
    stage_split(wptr + k0, wv, lBh, lBl, ar, ac);
    __syncthreads();
    s16x8 ah[4], al[4], bh[4], bl[4];
#pragma unroll
    for (int i = 0; i < 4; i++) {
      ah[i] = *(const s16x8*)&lAh[(wm + i * 16 + lrow) * LSTR + lk];
      al[i] = *(const s16x8*)&lAl[(wm + i * 16 + lrow) * LSTR + lk];
      bh[i] = *(const s16x8*)&lBh[(wn + i * 16 + lrow) * LSTR + lk];
      bl[i] = *(const s16x8*)&lBl[(wn + i * 16 + lrow) * LSTR + lk];
    }
#pragma unroll
    for (int mi = 0; mi < 4; mi++)
#pragma unroll
      for (int ni = 0; ni < 4; ni++) {
        f32x4 t = acc[mi][ni];
        t = mfma16(al[mi], bh[ni], t);
        t = mfma16(ah[mi], bl[ni], t);
        t = mfma16(ah[mi], bh[ni], t);
        acc[mi][ni] = t;
      }
    __syncthreads();
  }
  int rb = wm + (lane >> 4) * 4, cb = wn + (lane & 15);
#pragma unroll
  for (int mi = 0; mi < 4; mi++)
#pragma unroll
    for (int ni = 0; ni < 4; ni++) {
      int col = n0 + cb + ni * 16;
      if (col >= N) continue;
#pragma unroll
      for (int j = 0; j < 4; j++) {
        int row = m0 + rb + mi * 16 + j;
        if (row >= M) continue;
        float v = acc[mi][ni][j];
        if (EPI == 1) { v += bias[col]; v = (v > 20.f) ? v : log1pf(expf(v)); }
        C[(size_t)row * N + col] = v;
      }
    }
}

// ---------------- causal depthwise conv (K=4) + SiLU ----------------
__global__ __launch_bounds__(256) void conv_silu_k(
    const float* __restrict__ xz, const float* __restrict__ cw,
    const float* __restrict__ cb, float* __restrict__ xc)
{
  int idx = blockIdx.x * 256 + threadIdx.x;      // t*4096 + d
  int t = idx >> 12, d = idx & (DI - 1);
  f32x4 w = *(const f32x4*)(cw + d * 4);
  float acc = cb[d];
#pragma unroll
  for (int k = 0; k < 4; k++) {
    int ts = t - 3 + k;
    if (ts >= 0) acc = fmaf(xz[(size_t)ts * 8192 + d], w[k], acc);
  }
  float v = acc / (1.f + __expf(-acc));
  xc[idx] = v;
}

// ---------------- dt/B/C rmsnorms (row of 160 = 128+16+16) ----------------
__global__ void dtbc_norm_k(const float* __restrict__ xdb,
    const float* __restrict__ dtw, const float* __restrict__ bw, const float* __restrict__ cw,
    float* __restrict__ dtr, float* __restrict__ Bm, float* __restrict__ Cm)
{
  int t = blockIdx.x, lane = threadIdx.x;   // 64 threads
  const float* row = xdb + (size_t)t * 160;
  float v1 = row[lane], v2 = row[64 + lane];
  float vb = (lane < 32) ? row[128 + lane] : 0.f;
  float sd = wred64(v1 * v1 + v2 * v2);
  float sb = wred64((lane < 16) ? vb * vb : 0.f);
  float sc = wred64((lane >= 16 && lane < 32) ? vb * vb : 0.f);
  float scd = rsqrtf(sd * (1.f / 128) + 1e-6f);
  dtr[(size_t)t * 128 + lane]      = v1 * scd * dtw[lane];
  dtr[(size_t)t * 128 + 64 + lane] = v2 * scd * dtw[64 + lane];
  if (lane < 16)      Bm[t * 16 + lane]      = vb * rsqrtf(sb * (1.f / 16) + 1e-6f) * bw[lane];
  else if (lane < 32) Cm[t * 16 + lane - 16] = vb * rsqrtf(sc * (1.f / 16) + 1e-6f) * cw[lane - 16];
}

// ---------------- selective scan; y written IN PLACE over xc ----------------
__global__ __launch_bounds__(256) void scan_k(
    const float* __restrict__ dt, float* __restrict__ xcy,
    const float* __restrict__ xz, const float* __restrict__ Bm,
    const float* __restrict__ Cm, const float* __restrict__ A_log,
    const float* __restrict__ Dp)
{
  __shared__ float sdt[64][16], sxc[64][16], sz[64][16], sB[64][16], sC[64][16], sy[64][16];
  int tid = threadIdx.x;
  int dl = tid >> 4, n = tid & 15;
  int d0 = blockIdx.x * 16;
  int d = d0 + dl;
  float a = -__expf(A_log[d * 16 + n]);
  float dpar = Dp[d];
  float h = 0.f;
  for (int t0 = 0; t0 < LL; t0 += 64) {
#pragma unroll
    for (int i = 0; i < 4; i++) {
      int idx = i * 256 + tid;
      int tt = idx >> 4, c = idx & 15;
      int gt = t0 + tt;
      sdt[tt][c] = dt[(size_t)gt * DI + d0 + c];
      sxc[tt][c] = xcy[(size_t)gt * DI + d0 + c];
      sz[tt][c]  = xz[(size_t)gt * 8192 + DI + d0 + c];
      sB[tt][c]  = Bm[gt * 16 + c];
      sC[tt][c]  = Cm[gt * 16 + c];
    }
    __syncthreads();
    for (int tt = 0; tt < 64; tt++) {
      float dtv = sdt[tt][dl];
      float dA = __expf(dtv * a);
      h = h * dA + dtv * sxc[tt][dl] * sB[tt][n];
      float yc = h * sC[tt][n];
      yc += __shfl_xor(yc, 1, 64);
      yc += __shfl_xor(yc, 2, 64);
      yc += __shfl_xor(yc, 4, 64);
      yc += __shfl_xor(yc, 8, 64);
      if (n == 0) {
        float xv = sxc[tt][dl], zv = sz[tt][dl];
        sy[tt][dl] = (yc + xv * dpar) * (zv / (1.f + __expf(-zv)));
      }
    }
    __syncthreads();
#pragma unroll
    for (int i = 0; i < 4; i++) {
      int idx = i * 256 + tid;
      int tt = idx >> 4, c = idx & 15;
      xcy[(size_t)(t0 + tt) * DI + d0 + c] = sy[tt][c];
    }
    __syncthreads();
  }
}

// ---------------- router: logits + softmax + top-2 (fp32, tie -> lower index) ----------------
__global__ void router_topk_k(const float* __restrict__ hs2,
                              const float* __restrict__ rw,
                              int* __restrict__ topi, float* __restrict__ topv)
{
  int t = blockIdx.x, lane = threadIdx.x;   // 64 threads
  float acc[NEXP] = {};
  const float* xr = hs2 + (size_t)t * DMODEL;
  for (int i = lane; i < DMODEL; i += 64) {
    float x = xr[i];
#pragma unroll
    for (int e = 0; e < NEXP; e++) acc[e] += x * rw[e * DMODEL + i];
  }
#pragma unroll
  for (int e = 0; e < NEXP; e++) acc[e] = wred64(acc[e]);
  if (lane == 0) {
    float mx = acc[0];
#pragma unroll
    for (int e = 1; e < NEXP; e++) mx = fmaxf(mx, acc[e]);
    float p[NEXP], s = 0.f;
#pragma unroll
    for (int e = 0; e < NEXP; e++) { p[e] = expf(acc[e] - mx); s += p[e]; }
    float inv = 1.f / s;
#pragma unroll
    for (int e = 0; e < NEXP; e++) p[e] *= inv;
    int i0 = 0;
#pragma unroll
    for (int e = 1; e < NEXP; e++) if (p[e] > p[i0]) i0 = e;
    int i1 = (i0 == 0) ? 1 : 0;
#pragma unroll
    for (int e = 0; e < NEXP; e++) if (e != i0 && p[e] > p[i1]) i1 = e;
    topi[2 * t] = i0; topi[2 * t + 1] = i1;
    topv[2 * t] = p[i0]; topv[2 * t + 1] = p[i1];
  }
}

// ---------------- deterministic per-expert token lists (ballot prefix, no atomics) ----------------
__global__ void build_lists_k(const int* __restrict__ topi, const float* __restrict__ topv,
                              int* __restrict__ tok, float* __restrict__ gate,
                              int* __restrict__ slot, int* __restrict__ cnt,
                              int* __restrict__ offs)
{
  int lane = threadIdx.x;   // 64
  int base[NEXP] = {};
  for (int t0 = 0; t0 < LL; t0 += 64) {
    int t = t0 + lane;
    int i0 = topi[2 * t], i1 = topi[2 * t + 1];
    float p0 = topv[2 * t], p1 = topv[2 * t + 1];
    unsigned long long below = (1ull << lane) - 1ull;
#pragma unroll
    for (int e = 0; e < NEXP; e++) {
      unsigned long long m0 = __ballot(i0 == e);
      if (i0 == e) {
        int pos = base[e] + __popcll(m0 & below);
        tok[e * LL + pos] = t; gate[e * LL + pos] = p0; slot[e * LL + pos] = 0;
      }
      base[e] += __popcll(m0);
      unsigned long long m1 = __ballot(i1 == e);
      if (i1 == e) {
        int pos = base[e] + __popcll(m1 & below);
        tok[e * LL + pos] = t; gate[e * LL + pos] = p1; slot[e * LL + pos] = 1;
      }
      base[e] += __popcll(m1);
    }
  }
  if (lane < NEXP) cnt[lane] = base[lane];
  if (lane == 0) {
    int o = 0;
#pragma unroll
    for (int e = 0; e < NEXP; e++) { offs[e] = o; o += base[e]; }
  }
}

// ---------------- MoE phase 1: act = silu(X w1^T) * (X w3^T), gathered rows ----------------
__global__ __launch_bounds__(256) void moe_gemm1_k(
    const unsigned short* __restrict__ hs2b,
    const float* __restrict__ w1, const float* __restrict__ w3,
    unsigned short* __restrict__ act,
    const int* __restrict__ tok, const int* __restrict__ cnt, const int* __restrict__ offs)
{
  int e = blockIdx.z;
  int ce = cnt[e];
  int m0 = blockIdx.y * BM;
  if (m0 >= ce) return;
  int n0 = blockIdx.x * BN;
  __shared__ unsigned short lA[BM * LSTR];
  __shared__ unsigned short lB1[BN * LSTR];
  __shared__ unsigned short lB2[BN * LSTR];
  const float* W1 = w1 + (size_t)e * IFF * DMODEL;
  const float* W3 = w3 + (size_t)e * IFF * DMODEL;
  int tid = threadIdx.x;
  int lane = tid & 63, wave = tid >> 6;
  int wm = (wave >> 1) * 64, wn = (wave & 1) * 64;
  int lrow = lane & 15, lk = (lane >> 4) * 8;
  int ar = tid >> 1, ac = (tid & 1) * 16;
  bool av = (m0 + ar) < ce;
  const unsigned short* aptr = hs2b + (size_t)(av ? tok[e * LL + m0 + ar] : 0) * DMODEL + ac;
  const float* w1p = W1 + (size_t)(n0 + ar) * DMODEL + ac;
  const float* w3p = W3 + (size_t)(n0 + ar) * DMODEL + ac;
  f32x4 acc1[4][4] = {}, acc2[4][4] = {};
  for (int k0 = 0; k0 < DMODEL; k0 += BK) {
    stage_a_bf16(aptr + k0, av, lA, ar, ac);
    stage_w_f32(w1p + k0, true, lB1, ar, ac);
    stage_w_f32(w3p + k0, true, lB2, ar, ac);
    __syncthreads();
    s16x8 af[4];
#pragma unroll
    for (int i = 0; i < 4; i++)
      af[i] = *(const s16x8*)&lA[(wm + i * 16 + lrow) * LSTR + lk];
#pragma unroll
    for (int ni = 0; ni < 4; ni++) {
      s16x8 b1 = *(const s16x8*)&lB1[(wn + ni * 16 + lrow) * LSTR + lk];
#pragma unroll
      for (int mi = 0; mi < 4; mi++) acc1[mi][ni] = mfma16(af[mi], b1, acc1[mi][ni]);
      s16x8 b2 = *(const s16x8*)&lB2[(wn + ni * 16 + lrow) * LSTR + lk];
#pragma unroll
      for (int mi = 0; mi < 4; mi++) acc2[mi][ni] = mfma16(af[mi], b2, acc2[mi][ni]);
    }
    __syncthreads();
  }
  int rb = wm + (lane >> 4) * 4, cb = wn + (lane & 15);
  int obase = offs[e];
#pragma unroll
  for (int mi = 0; mi < 4; mi++)
#pragma unroll
    for (int j = 0; j < 4; j++) {
      int row = m0 + rb + mi * 16 + j;
      if (row >= ce) continue;
#pragma unroll
      for (int ni = 0; ni < 4; ni++) {
        int col = n0 + cb + ni * 16;
        float g = acc1[mi][ni][j], u = acc2[mi][ni][j];
        float aval = (g / (1.f + __expf(-g))) * u;
        act[(size_t)(obase + row) * IFF + col] = f2bf(aval);
      }
    }
}

// ---------------- MoE phase 2: yslot[slot][tok] = gate * (act w2^T) ----------------
__global__ __launch_bounds__(256) void moe_gemm2_k(
    const unsigned short* __restrict__ act, const float* __restrict__ w2,
    float* __restrict__ yslot,
    const int* __restrict__ tok, const float* __restrict__ gate,
    const int* __restrict__ slot, const int* __restrict__ cnt, const int* __restrict__ offs)
{
  int e = blockIdx.z;
  int ce = cnt[e];
  int m0 = blockIdx.y * BM;
  if (m0 >= ce) return;
  int n0 = blockIdx.x * BN;
  __shared__ unsigned short lA[BM * LSTR];
  __shared__ unsigned short lB[BN * LSTR];
  const float* W = w2 + (size_t)e * DMODEL * IFF;
  int obase = offs[e];
  int tid = threadIdx.x;
  int lane = tid & 63, wave = tid >> 6;
  int wm = (wave >> 1) * 64, wn = (wave & 1) * 64;
  int lrow = lane & 15, lk = (lane >> 4) * 8;
  int ar = tid >> 1, ac = (tid & 1) * 16;
  bool av = (m0 + ar) < ce;
  const unsigned short* aptr = act + (size_t)(obase + (av ? (m0 + ar) : 0)) * IFF + ac;
  const float* wp = W + (size_t)(n0 + ar) * IFF + ac;
  f32x4 acc[4][4] = {};
  for (int k0 = 0; k0 < IFF; k0 += BK) {
    stage_a_bf16(aptr + k0, av, lA, ar, ac);
    stage_w_f32(wp + k0, true, lB, ar, ac);
    __syncthreads();
    s16x8 af[4], bfr[4];
#pragma unroll
    for (int i = 0; i < 4; i++) {
      af[i]  = *(const s16x8*)&lA[(wm + i * 16 + lrow) * LSTR + lk];
      bfr[i] = *(const s16x8*)&lB[(wn + i * 16 + lrow) * LSTR + lk];
    }
#pragma unroll
    for (int mi = 0; mi < 4; mi++)
#pragma unroll
      for (int ni = 0; ni < 4; ni++)
        acc[mi][ni] = mfma16(af[mi], bfr[ni], acc[mi][ni]);
    __syncthreads();
  }
  int rb = wm + (lane >> 4) * 4, cb = wn + (lane & 15);
#pragma unroll
  for (int mi = 0; mi < 4; mi++)
#pragma unroll
    for (int j = 0; j < 4; j++) {
      int row = m0 + rb + mi * 16 + j;
      if (row >= ce) continue;
      int t = tok[e * LL + row];
      float g = gate[e * LL + row];
      int s = slot[e * LL + row];
      float* dst = yslot + ((size_t)s * LL + t) * DMODEL + n0 + cb;
#pragma unroll
      for (int ni = 0; ni < 4; ni++) dst[ni * 16] = acc[mi][ni][j] * g;
    }
}

// ---------------- combine the two routed-expert contributions ----------------
__global__ void moe_combine_k(const float* __restrict__ ys, float* __restrict__ out) {
  size_t i = ((size_t)blockIdx.x * 256 + threadIdx.x) * 4;
  f32x4 a = *(const f32x4*)(ys + i);
  f32x4 b = *(const f32x4*)(ys + (size_t)LL * DMODEL + i);
  *(f32x4*)(out + i) = a + b;
}

// ---------------- launch ----------------
extern "C" void kernel_launch(void* const* d_in, const int* in_sizes, int n_in,
                              void* d_out, int out_size, void* d_ws, size_t ws_size,
                              hipStream_t stream)
{
  (void)in_sizes; (void)n_in; (void)out_size; (void)ws_size;
  const float* hidden     = (const float*)d_in[0];
  const float* ln_in_w    = (const float*)d_in[1];
  const float* in_proj_w  = (const float*)d_in[2];
  const float* conv_w     = (const float*)d_in[3];
  const float* conv_b     = (const float*)d_in[4];
  const float* x_proj_w   = (const float*)d_in[5];
  const float* dt_ln_w    = (const float*)d_in[6];
  const float* b_ln_w     = (const float*)d_in[7];
  const float* c_ln_w     = (const float*)d_in[8];
  const float* dt_proj_w  = (const float*)d_in[9];
  const float* dt_proj_b  = (const float*)d_in[10];
  const float* A_log      = (const float*)d_in[11];
  const float* D_param    = (const float*)d_in[12];
  const float* out_proj_w = (const float*)d_in[13];
  const float* ln_ff_w    = (const float*)d_in[14];
  const float* router_w   = (const float*)d_in[15];
  const float* w1         = (const float*)d_in[16];
  const float* w3         = (const float*)d_in[17];
  const float* w2         = (const float*)d_in[18];
  float* moe_out  = (float*)d_out;
  float* residual = (float*)d_out + (size_t)LL * DMODEL;

  char* p = (char*)d_ws;
  auto alloc = [&](size_t bytes) { char* r = p; p += (bytes + 255) & ~(size_t)255; return r; };
  float* hs_f            = (float*)alloc((size_t)LL * DMODEL * 4);
  float* xz              = (float*)alloc((size_t)LL * 2 * DI * 4);   // later aliased by act_buf
  float* xc              = (float*)alloc((size_t)LL * DI * 4);       // conv out; scan writes y in place
  float* xdb             = (float*)alloc((size_t)LL * 160 * 4);
  float* dtr             = (float*)alloc((size_t)LL * 128 * 4);
  float* Bm              = (float*)alloc((size_t)LL * 16 * 4);
  float* Cm              = (float*)alloc((size_t)LL * 16 * 4);
  float* dt_full         = (float*)alloc((size_t)LL * DI * 4);       // later aliased by yslot
  float* mamba_out       = (float*)alloc((size_t)LL * DMODEL * 4);
  float* hs2_f           = (float*)alloc((size_t)LL * DMODEL * 4);
  unsigned short* hs2_bf = (unsigned short*)alloc((size_t)LL * DMODEL * 2);
  int* topi              = (int*)alloc(LL * 2 * 4);
  float* topv            = (float*)alloc(LL * 2 * 4);
  int* tok               = (int*)alloc(NEXP * LL * 4);
  float* gate            = (float*)alloc(NEXP * LL * 4);
  int* slot              = (int*)alloc(NEXP * LL * 4);
  int* cnt               = (int*)alloc(256);
  int* offs              = (int*)alloc(256);
  // aliases: regions whose producers/consumers are fully ordered before reuse
  unsigned short* act_buf = (unsigned short*)xz;   // 23.1 MB <= 33.5 MB, xz dead after scan_k
  float* yslot            = dt_full;               // 16.78 MB exact,   dt_full dead after scan_k

  rmsnorm_k<<<LL, 256, 0, stream>>>(hidden, ln_in_w, nullptr, nullptr, hs_f, nullptr);
  gemm_nt_split_k<0><<<dim3(64, 8), 256, 0, stream>>>(hs_f, in_proj_w, xz, LL, 2 * DI, DMODEL, nullptr);
  conv_silu_k<<<(LL * DI) / 256, 256, 0, stream>>>(xz, conv_w, conv_b, xc);
  gemm_nt_split_k<0><<<dim3(2, 8), 256, 0, stream>>>(xc, x_proj_w, xdb, LL, 160, DI, nullptr);
  dtbc_norm_k<<<LL, 64, 0, stream>>>(xdb, dt_ln_w, b_ln_w, c_ln_w, dtr, Bm, Cm);
  gemm_nt_split_k<1><<<dim3(32, 8), 256, 0, stream>>>(dtr, dt_proj_w, dt_full, LL, DI, RDT, dt_proj_b);
  scan_k<<<DI / 16, 256, 0, stream>>>(dt_full, xc, xz, Bm, Cm, A_log, D_param);
  gemm_nt_split_k<0><<<dim3(16, 8), 256, 0, stream>>>(xc, out_proj_w, mamba_out, LL, DMODEL, DI, nullptr);
  rmsnorm_k<<<LL, 256, 0, stream>>>(mamba_out, ln_ff_w, hidden, residual, hs2_f, hs2_bf);
  router_topk_k<<<LL, 64, 0, stream>>>(hs2_f, router_w, topi, topv);
  build_lists_k<<<1, 64, 0, stream>>>(topi, topv, tok, gate, slot, cnt, offs);
  moe_gemm1_k<<<dim3(44, 8, 8), 256, 0, stream>>>(hs2_bf, w1, w3, act_buf, tok, cnt, offs);
  moe_gemm2_k<<<dim3(16, 8, 8), 256, 0, stream>>>(act_buf, w2, yslot, tok, gate, slot, cnt, offs);
  moe_combine_k<<<(LL * DMODEL) / (256 * 4), 256, 0, stream>>>(yslot, moe_out);
}

// Round 3
// 1215.427 us; speedup vs baseline: 1.6324x; 1.6324x over previous
//
#include <hip/hip_runtime.h>
#include <hip/hip_bf16.h>
#include <stdint.h>

// ---------------- types / helpers ----------------
typedef __attribute__((ext_vector_type(4))) float f32x4;
typedef __attribute__((ext_vector_type(8))) short s16x8;          // MFMA bf16 frag
typedef __attribute__((ext_vector_type(8))) unsigned short u16x8;

#define LL 1024
#define DMODEL 2048
#define DI 4096
#define NSTATE 16
#define RDT 128
#define NEXP 8
#define IFF 5632

#define BM 128
#define BN 128
#define BK 32

__device__ inline unsigned short f2bf(float f) {            // fp32 -> bf16 RNE (bit ops)
  unsigned int u = __builtin_bit_cast(unsigned int, f);
  u += 0x7fffu + ((u >> 16) & 1u);
  return (unsigned short)(u >> 16);
}
__device__ inline unsigned short cvbf(float f) {            // compiler path (v_cvt_pk capable)
  return __builtin_bit_cast(unsigned short, __float2bfloat16(f));
}
__device__ inline float upbf(unsigned short h) {
  return __builtin_bit_cast(float, (unsigned int)h << 16);
}
__device__ inline float wred64(float v) {
#pragma unroll
  for (int m = 32; m; m >>= 1) v += __shfl_xor(v, m, 64);
  return v;
}
__device__ inline f32x4 mfma16(s16x8 a, s16x8 b, f32x4 c) {
  return __builtin_amdgcn_mfma_f32_16x16x32_bf16(a, b, c, 0, 0, 0);
}
// LDS tile index: row-major [128][32] bf16, XOR-swizzled 8-elem chunks (4-way max conflict)
__device__ inline int swz(int row, int chunk) {
  return row * 32 + (chunk ^ ((row & 3) << 3));
}
// convert 8 f32 (two f32x4) -> 8 bf16
__device__ inline void cv8(f32x4 a, f32x4 b, u16x8& h) {
#pragma unroll
  for (int j = 0; j < 4; j++) { h[j] = cvbf(a[j]); h[4 + j] = cvbf(b[j]); }
}
// split 8 f32 -> hi/lo bf16
__device__ inline void cv_split8(f32x4 a, f32x4 b, u16x8& h, u16x8& l) {
#pragma unroll
  for (int j = 0; j < 4; j++) {
    unsigned short hh = cvbf(a[j]); h[j] = hh; l[j] = cvbf(a[j] - upbf(hh));
    unsigned short hb = cvbf(b[j]); h[4 + j] = hb; l[4 + j] = cvbf(b[j] - upbf(hb));
  }
}

// ---------------- RMSNorm (optionally fused residual-add) ----------------
__global__ __launch_bounds__(256) void rmsnorm_k(
    const float* __restrict__ x, const float* __restrict__ w,
    const float* __restrict__ addin, float* __restrict__ resout,
    float* __restrict__ f32out, unsigned short* __restrict__ bf16out)
{
  int t = blockIdx.x, tid = threadIdx.x;
  size_t base = (size_t)t * DMODEL + tid * 8;
  f32x4 v0 = *(const f32x4*)(x + base);
  f32x4 v1 = *(const f32x4*)(x + base + 4);
  if (addin) {
    v0 += *(const f32x4*)(addin + base);
    v1 += *(const f32x4*)(addin + base + 4);
  }
  float ss = 0.f;
#pragma unroll
  for (int j = 0; j < 4; j++) ss += v0[j]*v0[j] + v1[j]*v1[j];
  ss = wred64(ss);
  __shared__ float sred[4];
  if ((tid & 63) == 0) sred[tid >> 6] = ss;
  __syncthreads();
  ss = sred[0] + sred[1] + sred[2] + sred[3];
  float sc = rsqrtf(ss * (1.f / DMODEL) + 1e-6f);
  if (resout) {
    *(f32x4*)(resout + base) = v0;
    *(f32x4*)(resout + base + 4) = v1;
  }
  f32x4 w0 = *(const f32x4*)(w + tid * 8);
  f32x4 w1 = *(const f32x4*)(w + tid * 8 + 4);
  f32x4 o0 = v0 * sc * w0, o1 = v1 * sc * w1;
  if (f32out) {
    *(f32x4*)(f32out + base) = o0;
    *(f32x4*)(f32out + base + 4) = o1;
  }
  if (bf16out) {
    u16x8 ob;
#pragma unroll
    for (int j = 0; j < 4; j++) { ob[j] = f2bf(o0[j]); ob[4 + j] = f2bf(o1[j]); }
    *(u16x8*)(bf16out + base) = ob;
  }
}

// ---------------- split-bf16 GEMM (pipelined, dbuf LDS, 1 barrier/iter) ----------------
// C[M,N] (+= part z) = A[M,K](f32) * W[N,K]^T(f32), 3-term split accumulation.
// EPI: 0 = plain, 1 = softplus(v + bias[col]); blockIdx.z = K-part (kchunk each)
template<int EPI>
__global__ __launch_bounds__(256) void gemm_split_k(
    const float* __restrict__ A, const float* __restrict__ W,
    float* __restrict__ C, int M, int N, int K, int kchunk,
    const float* __restrict__ bias)
{
  __shared__ unsigned short sA[2][2][128 * 32];   // [dbuf][hi/lo]
  __shared__ unsigned short sB[2][2][128 * 32];
  int tid = threadIdx.x;
  int n0 = blockIdx.x * BN, m0 = blockIdx.y * BM;
  int kbase = blockIdx.z * kchunk;
  C += (size_t)blockIdx.z * M * N;
  int lane = tid & 63, wave = tid >> 6;
  int wm = (wave >> 1) * 64, wn = (wave & 1) * 64;
  int lrow = lane & 15, lk = (lane >> 4) * 8;
  int ar = tid >> 1, ac = (tid & 1) * 16;
  int arow = m0 + ar; if (arow >= M) arow = M - 1;
  int wrow = n0 + ar; if (wrow >= N) wrow = N - 1;
  const float* aptr = A + (size_t)arow * K + kbase + ac;
  const float* wptr = W + (size_t)wrow * K + kbase + ac;
  f32x4 ra[4], rw[4];
#pragma unroll
  for (int q = 0; q < 4; q++) { ra[q] = *(const f32x4*)(aptr + 4*q); rw[q] = *(const f32x4*)(wptr + 4*q); }
  int NT = kchunk / BK;
  f32x4 acc[4][4] = {};
  int c0 = ac, c1 = ac + 8;
  for (int t = 0; t < NT; ++t) {
    int cur = t & 1;
    {
      u16x8 h0, l0, h1, l1;
      cv_split8(ra[0], ra[1], h0, l0);
      cv_split8(ra[2], ra[3], h1, l1);
      *(u16x8*)&sA[cur][0][swz(ar, c0)] = h0;
      *(u16x8*)&sA[cur][1][swz(ar, c0)] = l0;
      *(u16x8*)&sA[cur][0][swz(ar, c1)] = h1;
      *(u16x8*)&sA[cur][1][swz(ar, c1)] = l1;
      cv_split8(rw[0], rw[1], h0, l0);
      cv_split8(rw[2], rw[3], h1, l1);
      *(u16x8*)&sB[cur][0][swz(ar, c0)] = h0;
      *(u16x8*)&sB[cur][1][swz(ar, c0)] = l0;
      *(u16x8*)&sB[cur][0][swz(ar, c1)] = h1;
      *(u16x8*)&sB[cur][1][swz(ar, c1)] = l1;
    }
    if (t + 1 < NT) {
      int k0 = (t + 1) * BK;
#pragma unroll
      for (int q = 0; q < 4; q++) { ra[q] = *(const f32x4*)(aptr + k0 + 4*q); rw[q] = *(const f32x4*)(wptr + k0 + 4*q); }
    }
    __syncthreads();
    s16x8 ah[4], al[4];
#pragma unroll
    for (int i = 0; i < 4; i++) {
      int r = wm + i * 16 + lrow;
      ah[i] = *(const s16x8*)&sA[cur][0][swz(r, lk)];
      al[i] = *(const s16x8*)&sA[cur][1][swz(r, lk)];
    }
#pragma unroll
    for (int ni = 0; ni < 4; ni++) {
      int r = wn + ni * 16 + lrow;
      s16x8 bh = *(const s16x8*)&sB[cur][0][swz(r, lk)];
      s16x8 bl = *(const s16x8*)&sB[cur][1][swz(r, lk)];
#pragma unroll
      for (int mi = 0; mi < 4; mi++) {
        f32x4 tc = acc[mi][ni];
        tc = mfma16(al[mi], bh, tc);
        tc = mfma16(ah[mi], bl, tc);
        tc = mfma16(ah[mi], bh, tc);
        acc[mi][ni] = tc;
      }
    }
  }
  int rb = wm + (lane >> 4) * 4, cb = wn + (lane & 15);
#pragma unroll
  for (int mi = 0; mi < 4; mi++)
#pragma unroll
    for (int ni = 0; ni < 4; ni++) {
      int col = n0 + cb + ni * 16;
      if (col >= N) continue;
#pragma unroll
      for (int j = 0; j < 4; j++) {
        int row = m0 + rb + mi * 16 + j;
        if (row >= M) continue;
        float v = acc[mi][ni][j];
        if (EPI == 1) { v += bias[col]; v = (v > 20.f) ? v : log1pf(expf(v)); }
        C[(size_t)row * N + col] = v;
      }
    }
}

// ---------------- split-K partial reduction ----------------
__global__ void reduce_parts_k(const float* __restrict__ src, float* __restrict__ dst,
                               int len, int parts)
{
  int i = (blockIdx.x * 256 + threadIdx.x) * 4;
  if (i >= len) return;
  f32x4 s = *(const f32x4*)(src + i);
  for (int p = 1; p < parts; p++) s += *(const f32x4*)(src + (size_t)p * len + i);
  *(f32x4*)(dst + i) = s;
}

// ---------------- causal depthwise conv (K=4) + SiLU ----------------
__global__ __launch_bounds__(256) void conv_silu_k(
    const float* __restrict__ xz, const float* __restrict__ cw,
    const float* __restrict__ cb, float* __restrict__ xc)
{
  int idx = blockIdx.x * 256 + threadIdx.x;      // t*4096 + d
  int t = idx >> 12, d = idx & (DI - 1);
  f32x4 w = *(const f32x4*)(cw + d * 4);
  float acc = cb[d];
#pragma unroll
  for (int k = 0; k < 4; k++) {
    int ts = t - 3 + k;
    if (ts >= 0) acc = fmaf(xz[(size_t)ts * 8192 + d], w[k], acc);
  }
  float v = acc / (1.f + __expf(-acc));
  xc[idx] = v;
}

// ---------------- dt/B/C rmsnorms (row of 160 = 128+16+16) ----------------
__global__ void dtbc_norm_k(const float* __restrict__ xdb,
    const float* __restrict__ dtw, const float* __restrict__ bw, const float* __restrict__ cw,
    float* __restrict__ dtr, float* __restrict__ Bm, float* __restrict__ Cm)
{
  int t = blockIdx.x, lane = threadIdx.x;   // 64 threads
  const float* row = xdb + (size_t)t * 160;
  float v1 = row[lane], v2 = row[64 + lane];
  float vb = (lane < 32) ? row[128 + lane] : 0.f;
  float sd = wred64(v1 * v1 + v2 * v2);
  float sb = wred64((lane < 16) ? vb * vb : 0.f);
  float sc = wred64((lane >= 16 && lane < 32) ? vb * vb : 0.f);
  float scd = rsqrtf(sd * (1.f / 128) + 1e-6f);
  dtr[(size_t)t * 128 + lane]      = v1 * scd * dtw[lane];
  dtr[(size_t)t * 128 + 64 + lane] = v2 * scd * dtw[64 + lane];
  if (lane < 16)      Bm[t * 16 + lane]      = vb * rsqrtf(sb * (1.f / 16) + 1e-6f) * bw[lane];
  else if (lane < 32) Cm[t * 16 + lane - 16] = vb * rsqrtf(sc * (1.f / 16) + 1e-6f) * cw[lane - 16];
}

// ---------------- selective scan; y written IN PLACE over xc ----------------
__global__ __launch_bounds__(256) void scan_k(
    const float* __restrict__ dt, float* __restrict__ xcy,
    const float* __restrict__ xz, const float* __restrict__ Bm,
    const float* __restrict__ Cm, const float* __restrict__ A_log,
    const float* __restrict__ Dp)
{
  __shared__ float sdt[64][16], sxc[64][16], sz[64][16], sB[64][16], sC[64][16], sy[64][16];
  int tid = threadIdx.x;
  int dl = tid >> 4, n = tid & 15;
  int d0 = blockIdx.x * 16;
  int d = d0 + dl;
  float a = -__expf(A_log[d * 16 + n]);
  float dpar = Dp[d];
  float h = 0.f;
  for (int t0 = 0; t0 < LL; t0 += 64) {
#pragma unroll
    for (int i = 0; i < 4; i++) {
      int idx = i * 256 + tid;
      int tt = idx >> 4, c = idx & 15;
      int gt = t0 + tt;
      sdt[tt][c] = dt[(size_t)gt * DI + d0 + c];
      sxc[tt][c] = xcy[(size_t)gt * DI + d0 + c];
      sz[tt][c]  = xz[(size_t)gt * 8192 + DI + d0 + c];
      sB[tt][c]  = Bm[gt * 16 + c];
      sC[tt][c]  = Cm[gt * 16 + c];
    }
    __syncthreads();
    for (int tt = 0; tt < 64; tt++) {
      float dtv = sdt[tt][dl];
      float dA = __expf(dtv * a);
      h = h * dA + dtv * sxc[tt][dl] * sB[tt][n];
      float yc = h * sC[tt][n];
      yc += __shfl_xor(yc, 1, 64);
      yc += __shfl_xor(yc, 2, 64);
      yc += __shfl_xor(yc, 4, 64);
      yc += __shfl_xor(yc, 8, 64);
      if (n == 0) {
        float xv = sxc[tt][dl], zv = sz[tt][dl];
        sy[tt][dl] = (yc + xv * dpar) * (zv / (1.f + __expf(-zv)));
      }
    }
    __syncthreads();
#pragma unroll
    for (int i = 0; i < 4; i++) {
      int idx = i * 256 + tid;
      int tt = idx >> 4, c = idx & 15;
      xcy[(size_t)(t0 + tt) * DI + d0 + c] = sy[tt][c];
    }
    __syncthreads();
  }
}

// ---------------- router: logits + softmax + top-2 ----------------
__global__ void router_topk_k(const float* __restrict__ hs2,
                              const float* __restrict__ rw,
                              int* __restrict__ topi, float* __restrict__ topv)
{
  int t = blockIdx.x, lane = threadIdx.x;   // 64 threads
  float acc[NEXP] = {};
  const float* xr = hs2 + (size_t)t * DMODEL;
  for (int i = lane; i < DMODEL; i += 64) {
    float x = xr[i];
#pragma unroll
    for (int e = 0; e < NEXP; e++) acc[e] += x * rw[e * DMODEL + i];
  }
#pragma unroll
  for (int e = 0; e < NEXP; e++) acc[e] = wred64(acc[e]);
  if (lane == 0) {
    float mx = acc[0];
#pragma unroll
    for (int e = 1; e < NEXP; e++) mx = fmaxf(mx, acc[e]);
    float p[NEXP], s = 0.f;
#pragma unroll
    for (int e = 0; e < NEXP; e++) { p[e] = expf(acc[e] - mx); s += p[e]; }
    float inv = 1.f / s;
#pragma unroll
    for (int e = 0; e < NEXP; e++) p[e] *= inv;
    int i0 = 0;
#pragma unroll
    for (int e = 1; e < NEXP; e++) if (p[e] > p[i0]) i0 = e;
    int i1 = (i0 == 0) ? 1 : 0;
#pragma unroll
    for (int e = 0; e < NEXP; e++) if (e != i0 && p[e] > p[i1]) i1 = e;
    topi[2 * t] = i0; topi[2 * t + 1] = i1;
    topv[2 * t] = p[i0]; topv[2 * t + 1] = p[i1];
  }
}

// ---------------- deterministic per-expert token lists ----------------
__global__ void build_lists_k(const int* __restrict__ topi, const float* __restrict__ topv,
                              int* __restrict__ tok, float* __restrict__ gate,
                              int* __restrict__ slot, int* __restrict__ cnt,
                              int* __restrict__ offs)
{
  int lane = threadIdx.x;   // 64
  int base[NEXP] = {};
  for (int t0 = 0; t0 < LL; t0 += 64) {
    int t = t0 + lane;
    int i0 = topi[2 * t], i1 = topi[2 * t + 1];
    float p0 = topv[2 * t], p1 = topv[2 * t + 1];
    unsigned long long below = (1ull << lane) - 1ull;
#pragma unroll
    for (int e = 0; e < NEXP; e++) {
      unsigned long long m0 = __ballot(i0 == e);
      if (i0 == e) {
        int pos = base[e] + __popcll(m0 & below);
        tok[e * LL + pos] = t; gate[e * LL + pos] = p0; slot[e * LL + pos] = 0;
      }
      base[e] += __popcll(m0);
      unsigned long long m1 = __ballot(i1 == e);
      if (i1 == e) {
        int pos = base[e] + __popcll(m1 & below);
        tok[e * LL + pos] = t; gate[e * LL + pos] = p1; slot[e * LL + pos] = 1;
      }
      base[e] += __popcll(m1);
    }
  }
  if (lane < NEXP) cnt[lane] = base[lane];
  if (lane == 0) {
    int o = 0;
#pragma unroll
    for (int e = 0; e < NEXP; e++) { offs[e] = o; o += base[e]; }
  }
}

// ---------------- MoE phase 1 (pipelined): act = silu(X w1^T) * (X w3^T) ----------------
__global__ __launch_bounds__(256) void moe_gemm1_k(
    const unsigned short* __restrict__ hs2b,
    const float* __restrict__ w1, const float* __restrict__ w3,
    unsigned short* __restrict__ act,
    const int* __restrict__ tok, const int* __restrict__ cnt, const int* __restrict__ offs)
{
  int e = blockIdx.z;
  int ce = cnt[e];
  int m0 = blockIdx.y * BM;
  if (m0 >= ce) return;
  int n0 = blockIdx.x * BN;
  __shared__ unsigned short sA[2][128 * 32];
  __shared__ unsigned short sB1[2][128 * 32];
  __shared__ unsigned short sB2[2][128 * 32];
  const float* W1 = w1 + (size_t)e * IFF * DMODEL;
  const float* W3 = w3 + (size_t)e * IFF * DMODEL;
  int tid = threadIdx.x;
  int lane = tid & 63, wave = tid >> 6;
  int wm = (wave >> 1) * 64, wn = (wave & 1) * 64;
  int lrow = lane & 15, lk = (lane >> 4) * 8;
  int ar = tid >> 1, ac = (tid & 1) * 16;
  bool av = (m0 + ar) < ce;
  const unsigned short* aptr = hs2b + (size_t)(av ? tok[e * LL + m0 + ar] : 0) * DMODEL + ac;
  const float* w1p = W1 + (size_t)(n0 + ar) * DMODEL + ac;
  const float* w3p = W3 + (size_t)(n0 + ar) * DMODEL + ac;
  u16x8 ua0, ua1;
  f32x4 r1[4], r3[4];
  ua0 = *(const u16x8*)(aptr); ua1 = *(const u16x8*)(aptr + 8);
#pragma unroll
  for (int q = 0; q < 4; q++) { r1[q] = *(const f32x4*)(w1p + 4*q); r3[q] = *(const f32x4*)(w3p + 4*q); }
  f32x4 acc1[4][4] = {}, acc2[4][4] = {};
  int c0 = ac, c1 = ac + 8;
  const int NT = DMODEL / BK;
  for (int t = 0; t < NT; ++t) {
    int cur = t & 1;
    *(u16x8*)&sA[cur][swz(ar, c0)] = ua0;
    *(u16x8*)&sA[cur][swz(ar, c1)] = ua1;
    u16x8 h;
    cv8(r1[0], r1[1], h); *(u16x8*)&sB1[cur][swz(ar, c0)] = h;
    cv8(r1[2], r1[3], h); *(u16x8*)&sB1[cur][swz(ar, c1)] = h;
    cv8(r3[0], r3[1], h); *(u16x8*)&sB2[cur][swz(ar, c0)] = h;
    cv8(r3[2], r3[3], h); *(u16x8*)&sB2[cur][swz(ar, c1)] = h;
    if (t + 1 < NT) {
      int k0 = (t + 1) * BK;
      ua0 = *(const u16x8*)(aptr + k0); ua1 = *(const u16x8*)(aptr + k0 + 8);
#pragma unroll
      for (int q = 0; q < 4; q++) { r1[q] = *(const f32x4*)(w1p + k0 + 4*q); r3[q] = *(const f32x4*)(w3p + k0 + 4*q); }
    }
    __syncthreads();
    s16x8 af[4];
#pragma unroll
    for (int i = 0; i < 4; i++)
      af[i] = *(const s16x8*)&sA[cur][swz(wm + i * 16 + lrow, lk)];
#pragma unroll
    for (int ni = 0; ni < 4; ni++) {
      int r = wn + ni * 16 + lrow;
      s16x8 b1 = *(const s16x8*)&sB1[cur][swz(r, lk)];
      s16x8 b2 = *(const s16x8*)&sB2[cur][swz(r, lk)];
#pragma unroll
      for (int mi = 0; mi < 4; mi++) acc1[mi][ni] = mfma16(af[mi], b1, acc1[mi][ni]);
#pragma unroll
      for (int mi = 0; mi < 4; mi++) acc2[mi][ni] = mfma16(af[mi], b2, acc2[mi][ni]);
    }
  }
  int rb = wm + (lane >> 4) * 4, cb = wn + (lane & 15);
  int obase = offs[e];
#pragma unroll
  for (int mi = 0; mi < 4; mi++)
#pragma unroll
    for (int j = 0; j < 4; j++) {
      int row = m0 + rb + mi * 16 + j;
      if (row >= ce) continue;
#pragma unroll
      for (int ni = 0; ni < 4; ni++) {
        int col = n0 + cb + ni * 16;
        float g = acc1[mi][ni][j], u = acc2[mi][ni][j];
        float aval = (g / (1.f + __expf(-g))) * u;
        act[(size_t)(obase + row) * IFF + col] = f2bf(aval);
      }
    }
}

// ---------------- MoE phase 2 (pipelined): yslot = gate * (act w2^T) ----------------
__global__ __launch_bounds__(256) void moe_gemm2_k(
    const unsigned short* __restrict__ act, const float* __restrict__ w2,
    float* __restrict__ yslot,
    const int* __restrict__ tok, const float* __restrict__ gate,
    const int* __restrict__ slot, const int* __restrict__ cnt, const int* __restrict__ offs)
{
  int e = blockIdx.z;
  int ce = cnt[e];
  int m0 = blockIdx.y * BM;
  if (m0 >= ce) return;
  int n0 = blockIdx.x * BN;
  __shared__ unsigned short sA[2][128 * 32];
  __shared__ unsigned short sB[2][128 * 32];
  const float* W = w2 + (size_t)e * DMODEL * IFF;
  int obase = offs[e];
  int tid = threadIdx.x;
  int lane = tid & 63, wave = tid >> 6;
  int wm = (wave >> 1) * 64, wn = (wave & 1) * 64;
  int lrow = lane & 15, lk = (lane >> 4) * 8;
  int ar = tid >> 1, ac = (tid & 1) * 16;
  bool av = (m0 + ar) < ce;
  const unsigned short* aptr = act + (size_t)(obase + (av ? (m0 + ar) : 0)) * IFF + ac;
  const float* wp = W + (size_t)(n0 + ar) * IFF + ac;
  u16x8 ua0, ua1;
  f32x4 rw[4];
  ua0 = *(const u16x8*)(aptr); ua1 = *(const u16x8*)(aptr + 8);
#pragma unroll
  for (int q = 0; q < 4; q++) rw[q] = *(const f32x4*)(wp + 4*q);
  f32x4 acc[4][4] = {};
  int c0 = ac, c1 = ac + 8;
  const int NT = IFF / BK;
  for (int t = 0; t < NT; ++t) {
    int cur = t & 1;
    *(u16x8*)&sA[cur][swz(ar, c0)] = ua0;
    *(u16x8*)&sA[cur][swz(ar, c1)] = ua1;
    u16x8 h;
    cv8(rw[0], rw[1], h); *(u16x8*)&sB[cur][swz(ar, c0)] = h;
    cv8(rw[2], rw[3], h); *(u16x8*)&sB[cur][swz(ar, c1)] = h;
    if (t + 1 < NT) {
      int k0 = (t + 1) * BK;
      ua0 = *(const u16x8*)(aptr + k0); ua1 = *(const u16x8*)(aptr + k0 + 8);
#pragma unroll
      for (int q = 0; q < 4; q++) rw[q] = *(const f32x4*)(wp + k0 + 4*q);
    }
    __syncthreads();
    s16x8 af[4];
#pragma unroll
    for (int i = 0; i < 4; i++)
      af[i] = *(const s16x8*)&sA[cur][swz(wm + i * 16 + lrow, lk)];
#pragma unroll
    for (int ni = 0; ni < 4; ni++) {
      s16x8 b = *(const s16x8*)&sB[cur][swz(wn + ni * 16 + lrow, lk)];
#pragma unroll
      for (int mi = 0; mi < 4; mi++) acc[mi][ni] = mfma16(af[mi], b, acc[mi][ni]);
    }
  }
  int rb = wm + (lane >> 4) * 4, cb = wn + (lane & 15);
#pragma unroll
  for (int mi = 0; mi < 4; mi++)
#pragma unroll
    for (int j = 0; j < 4; j++) {
      int row = m0 + rb + mi * 16 + j;
      if (row >= ce) continue;
      int t = tok[e * LL + row];
      float g = gate[e * LL + row];
      int s = slot[e * LL + row];
      float* dst = yslot + ((size_t)s * LL + t) * DMODEL + n0 + cb;
#pragma unroll
      for (int ni = 0; ni < 4; ni++) dst[ni * 16] = acc[mi][ni][j] * g;
    }
}

// ---------------- combine the two routed-expert contributions ----------------
__global__ void moe_combine_k(const float* __restrict__ ys, float* __restrict__ out) {
  size_t i = ((size_t)blockIdx.x * 256 + threadIdx.x) * 4;
  f32x4 a = *(const f32x4*)(ys + i);
  f32x4 b = *(const f32x4*)(ys + (size_t)LL * DMODEL + i);
  *(f32x4*)(out + i) = a + b;
}

// ---------------- launch ----------------
extern "C" void kernel_launch(void* const* d_in, const int* in_sizes, int n_in,
                              void* d_out, int out_size, void* d_ws, size_t ws_size,
                              hipStream_t stream)
{
  (void)in_sizes; (void)n_in; (void)out_size; (void)ws_size;
  const float* hidden     = (const float*)d_in[0];
  const float* ln_in_w    = (const float*)d_in[1];
  const float* in_proj_w  = (const float*)d_in[2];
  const float* conv_w     = (const float*)d_in[3];
  const float* conv_b     = (const float*)d_in[4];
  const float* x_proj_w   = (const float*)d_in[5];
  const float* dt_ln_w    = (const float*)d_in[6];
  const float* b_ln_w     = (const float*)d_in[7];
  const float* c_ln_w     = (const float*)d_in[8];
  const float* dt_proj_w  = (const float*)d_in[9];
  const float* dt_proj_b  = (const float*)d_in[10];
  const float* A_log      = (const float*)d_in[11];
  const float* D_param    = (const float*)d_in[12];
  const float* out_proj_w = (const float*)d_in[13];
  const float* ln_ff_w    = (const float*)d_in[14];
  const float* router_w   = (const float*)d_in[15];
  const float* w1         = (const float*)d_in[16];
  const float* w3         = (const float*)d_in[17];
  const float* w2         = (const float*)d_in[18];
  float* moe_out  = (float*)d_out;
  float* residual = (float*)d_out + (size_t)LL * DMODEL;

  char* p = (char*)d_ws;
  auto alloc = [&](size_t bytes) { char* r = p; p += (bytes + 255) & ~(size_t)255; return r; };
  float* hs_f            = (float*)alloc((size_t)LL * DMODEL * 4);   // dead after in_proj -> xdb_parts
  float* xz              = (float*)alloc((size_t)LL * 2 * DI * 4);   // dead after scan -> act_buf
  float* xc              = (float*)alloc((size_t)LL * DI * 4);       // conv out; scan writes y in place
  float* xdb             = (float*)alloc((size_t)LL * 160 * 4);
  float* dtr             = (float*)alloc((size_t)LL * 128 * 4);
  float* Bm              = (float*)alloc((size_t)LL * 16 * 4);
  float* Cm              = (float*)alloc((size_t)LL * 16 * 4);
  float* dt_full         = (float*)alloc((size_t)LL * DI * 4);       // dead after scan -> out_parts -> yslot
  float* mamba_out       = (float*)alloc((size_t)LL * DMODEL * 4);
  float* hs2_f           = (float*)alloc((size_t)LL * DMODEL * 4);
  unsigned short* hs2_bf = (unsigned short*)alloc((size_t)LL * DMODEL * 2);
  int* topi              = (int*)alloc(LL * 2 * 4);
  float* topv            = (float*)alloc(LL * 2 * 4);
  int* tok               = (int*)alloc(NEXP * LL * 4);
  float* gate            = (float*)alloc(NEXP * LL * 4);
  int* slot              = (int*)alloc(NEXP * LL * 4);
  int* cnt               = (int*)alloc(256);
  int* offs              = (int*)alloc(256);
  // aliases (lifetimes strictly ordered by stream):
  unsigned short* act_buf = (unsigned short*)xz;   // 23.1 MB <= 33.5 MB
  float* out_parts        = dt_full;               // 16.78 MB exact (2 parts x 8.39)
  float* yslot            = dt_full;               // after out-reduce done
  float* xdb_parts        = hs_f;                  // 5.24 MB <= 8.39 MB

  rmsnorm_k<<<LL, 256, 0, stream>>>(hidden, ln_in_w, nullptr, nullptr, hs_f, nullptr);
  gemm_split_k<0><<<dim3(64, 8, 1), 256, 0, stream>>>(hs_f, in_proj_w, xz, LL, 2 * DI, DMODEL, DMODEL, nullptr);
  conv_silu_k<<<(LL * DI) / 256, 256, 0, stream>>>(xz, conv_w, conv_b, xc);
  gemm_split_k<0><<<dim3(2, 8, 8), 256, 0, stream>>>(xc, x_proj_w, xdb_parts, LL, 160, DI, DI / 8, nullptr);
  reduce_parts_k<<<(LL * 160) / 1024, 256, 0, stream>>>(xdb_parts, xdb, LL * 160, 8);
  dtbc_norm_k<<<LL, 64, 0, stream>>>(xdb, dt_ln_w, b_ln_w, c_ln_w, dtr, Bm, Cm);
  gemm_split_k<1><<<dim3(32, 8, 1), 256, 0, stream>>>(dtr, dt_proj_w, dt_full, LL, DI, RDT, RDT, dt_proj_b);
  scan_k<<<DI / 16, 256, 0, stream>>>(dt_full, xc, xz, Bm, Cm, A_log, D_param);
  gemm_split_k<0><<<dim3(16, 8, 2), 256, 0, stream>>>(xc, out_proj_w, out_parts, LL, DMODEL, DI, DI / 2, nullptr);
  reduce_parts_k<<<(LL * DMODEL) / 1024, 256, 0, stream>>>(out_parts, mamba_out, LL * DMODEL, 2);
  rmsnorm_k<<<LL, 256, 0, stream>>>(mamba_out, ln_ff_w, hidden, residual, hs2_f, hs2_bf);
  router_topk_k<<<LL, 64, 0, stream>>>(hs2_f, router_w, topi, topv);
  build_lists_k<<<1, 64, 0, stream>>>(topi, topv, tok, gate, slot, cnt, offs);
  moe_gemm1_k<<<dim3(44, 8, 8), 256, 0, stream>>>(hs2_bf, w1, w3, act_buf, tok, cnt, offs);
  moe_gemm2_k<<<dim3(16, 8, 8), 256, 0, stream>>>(act_buf, w2, yslot, tok, gate, slot, cnt, offs);
  moe_combine_k<<<(LL * DMODEL) / (256 * 4), 256, 0, stream>>>(yslot, moe_out);
}